// Round 2
// baseline (11400.770 us; speedup 1.0000x reference)
//
#include <hip/hip_runtime.h>

#define S_LEN 8192
#define DIN 120
#define HID 64
#define G4 256
#define NOUT 10
#define DHPM 258

// ---------------- workspace layout (float offsets) ----------------
static constexpr size_t OFF_PRE0 = 0;                                  // [S][256]
static constexpr size_t OFF_ACT0 = OFF_PRE0 + (size_t)S_LEN * G4;      // [S][256] activated gates L0
static constexpr size_t OFF_ACT1 = OFF_ACT0 + (size_t)S_LEN * G4;      // [S][256] activated gates L1
static constexpr size_t OFF_H0S  = OFF_ACT1 + (size_t)S_LEN * G4;      // [S+1][64]  row t+1 = h0 after step t, row0 = 0
static constexpr size_t OFF_C0S  = OFF_H0S + (size_t)(S_LEN + 1) * HID;
static constexpr size_t OFF_H1S  = OFF_C0S + (size_t)(S_LEN + 1) * HID; // [S+2][64] row t+2 = h1 after step t
static constexpr size_t OFF_C1S  = OFF_H1S + (size_t)(S_LEN + 2) * HID;
static constexpr size_t OFF_GOH  = OFF_C1S + (size_t)(S_LEN + 2) * HID; // [S][64]
static constexpr size_t OFF_GWS  = OFF_GOH + (size_t)S_LEN * HID;       // [S][120]
static constexpr size_t OFF_PMN  = OFF_GWS + (size_t)S_LEN * DIN;       // [2][64][64]
static constexpr size_t OFF_PMX  = OFF_PMN + 2 * 64 * 64;
static constexpr size_t OFF_MN   = OFF_PMX + 2 * 64 * 64;               // [2][64]
static constexpr size_t OFF_INV  = OFF_MN + 128;                        // [2][64]
static constexpr size_t OFF_WSUM = OFF_INV + 128;                       // [64]
static constexpr size_t OFF_S2   = OFF_WSUM + 64;                       // [2]

__device__ __forceinline__ float sig_(float x)  { return 1.0f / (1.0f + __expf(-x)); }
__device__ __forceinline__ float tanh_(float x) { return 1.0f - 2.0f / (__expf(2.0f * x) + 1.0f); }

// ---------------- prep: wsum = colsum(Wlin), s2 = colsum(Whpm2) ----------------
__global__ __launch_bounds__(128) void wl_prep_kernel(const float* __restrict__ Wlin,
                                                      const float* __restrict__ Whpm2,
                                                      float* __restrict__ ws) {
  int i = threadIdx.x;
  if (i < HID) {
    float s = 0.0f;
    for (int o = 0; o < NOUT; ++o) s += Wlin[o * HID + i];
    ws[OFF_WSUM + i] = s;
  } else if (i < HID + 2) {
    int h = i - HID;
    float s = 0.0f;
    for (int d = 0; d < DIN; ++d) s += Whpm2[d * 2 + h];
    ws[OFF_S2 + h] = s;
  }
}

// ---------------- pre0 = input @ Wih0.T + bih0 + bhh0 (8 timesteps per block) ----------------
__global__ __launch_bounds__(256) void wl_pre0_kernel(const float* __restrict__ input,
                                                      const float* __restrict__ Wih0,
                                                      const float* __restrict__ bih0,
                                                      const float* __restrict__ bhh0,
                                                      float* __restrict__ ws) {
  __shared__ __align__(16) float xin[8 * DIN];
  int tid = threadIdx.x;
  size_t t0 = (size_t)blockIdx.x * 8;
  for (int idx = tid; idx < 8 * DIN; idx += 256) xin[idx] = input[t0 * DIN + idx];
  float4 w[30];
  const float4* wr = (const float4*)(Wih0 + (size_t)tid * DIN);
#pragma unroll
  for (int i = 0; i < 30; ++i) w[i] = wr[i];
  float b = bih0[tid] + bhh0[tid];
  __syncthreads();
#pragma unroll
  for (int tt = 0; tt < 8; ++tt) {
    const float4* x4 = (const float4*)(xin + tt * DIN);
    float acc = b;
#pragma unroll
    for (int i = 0; i < 30; ++i) {
      float4 x = x4[i];
      acc += w[i].x * x.x + w[i].y * x.y + w[i].z * x.z + w[i].w * x.w;
    }
    ws[OFF_PRE0 + (t0 + tt) * G4 + tid] = acc;
  }
}

// ---------------- sequential scan: one barrier per superstep ----------------
// 8 waves. Waves 0-3: layer0, waves 4-7: layer1 (lagging one superstep).
// Lane mapping within a layer: wave-in-layer wl, lane l -> unit u = wl*16 + (l&15),
// gate grp = l>>4 (0=i,1=f,2=g,3=o), weight row r = grp*64 + u.
// All 4 gates of a unit live in one wave -> gate exchange via __shfl_down,
// c stays register-resident in the grp==0 lanes. h double-buffered in LDS.
__global__ __launch_bounds__(512, 2) void wl_scan_kernel(const float* __restrict__ Whh0,
                                                         const float* __restrict__ Wih1,
                                                         const float* __restrict__ Whh1,
                                                         const float* __restrict__ bih1,
                                                         const float* __restrict__ bhh1,
                                                         float* __restrict__ ws) {
  __shared__ __align__(16) float hbuf[2][2][HID];  // [buf][layer][unit]
  float* ACT0 = ws + OFF_ACT0;
  float* ACT1 = ws + OFF_ACT1;
  float* H0S = ws + OFF_H0S;
  float* C0S = ws + OFF_C0S;
  float* H1S = ws + OFF_H1S;
  float* C1S = ws + OFF_C1S;
  const float* PRE0 = ws + OFF_PRE0;

  int tid = threadIdx.x;
  int w = tid >> 6;
  int l = tid & 63;
  int grp = l >> 4;
  int un = l & 15;
  bool isL1 = (w >= 4);
  int li = isL1 ? 1 : 0;
  int wl = isL1 ? (w - 4) : w;
  int u = wl * 16 + un;
  int r = grp * 64 + u;

  // activation constants: grp==2 -> tanh(x)=2/(1+e^{-2x})-1 ; else sigmoid(x)=1/(1+e^{-x})
  float m = (grp == 2) ? -2.0f : -1.0f;
  float fa = (grp == 2) ? 2.0f : 1.0f;
  float fb = (grp == 2) ? -1.0f : 0.0f;

  float4 wa[16], wb[16];
  float b1 = 0.0f;
  if (!isL1) {
    const float4* W = (const float4*)(Whh0 + (size_t)r * HID);
#pragma unroll
    for (int i = 0; i < 16; ++i) wa[i] = W[i];
  } else {
    const float4* Wi = (const float4*)(Wih1 + (size_t)r * HID);
    const float4* Wh = (const float4*)(Whh1 + (size_t)r * HID);
#pragma unroll
    for (int i = 0; i < 16; ++i) { wa[i] = Wi[i]; wb[i] = Wh[i]; }
    b1 = bih1[r] + bhh1[r];
  }

  // init LDS h buffers and boundary rows of the global state arrays
  if (tid < 256) ((float*)hbuf)[tid] = 0.0f;
  if (tid < HID) {
    H0S[tid] = 0.0f; C0S[tid] = 0.0f;
    H1S[tid] = 0.0f; H1S[HID + tid] = 0.0f;
    C1S[tid] = 0.0f; C1S[HID + tid] = 0.0f;
  }
  float cc = 0.0f;
  float pre_n = (!isL1) ? PRE0[r] : 0.0f;
  __syncthreads();

  for (int s = 0; s <= S_LEN; ++s) {
    int rb = s & 1, wbuf = rb ^ 1;
    float a = 0.0f;
    bool act;
    int t;
    if (!isL1) {
      t = s;
      act = (s < S_LEN);
      if (act) {
        float4 s4 = make_float4(pre_n, 0.0f, 0.0f, 0.0f);
        const float4* h4 = (const float4*)hbuf[rb][0];
        if (s + 1 < S_LEN) pre_n = PRE0[(size_t)(s + 1) * G4 + r];  // prefetch
#pragma unroll
        for (int i = 0; i < 16; ++i) {
          float4 h = h4[i];
          s4.x += wa[i].x * h.x; s4.y += wa[i].y * h.y;
          s4.z += wa[i].z * h.z; s4.w += wa[i].w * h.w;
        }
        float acc = (s4.x + s4.y) + (s4.z + s4.w);
        float e = __expf(m * acc);
        a = fa / (1.0f + e) + fb;
        ACT0[(size_t)t * G4 + r] = a;
      }
    } else {
      t = s - 1;
      act = (s >= 1);
      if (act) {
        float4 s4 = make_float4(b1, 0.0f, 0.0f, 0.0f);
        float4 s5 = make_float4(0.0f, 0.0f, 0.0f, 0.0f);
        const float4* h4 = (const float4*)hbuf[rb][0];  // h0[t]
        const float4* g4 = (const float4*)hbuf[rb][1];  // h1[t-1]
#pragma unroll
        for (int i = 0; i < 16; ++i) {
          float4 h = h4[i]; float4 g = g4[i];
          s4.x += wa[i].x * h.x; s4.y += wa[i].y * h.y;
          s4.z += wa[i].z * h.z; s4.w += wa[i].w * h.w;
          s5.x += wb[i].x * g.x; s5.y += wb[i].y * g.y;
          s5.z += wb[i].z * g.z; s5.w += wb[i].w * g.w;
        }
        float acc = ((s4.x + s4.y) + (s4.z + s4.w)) + ((s5.x + s5.y) + (s5.z + s5.w));
        float e = __expf(m * acc);
        a = fa / (1.0f + e) + fb;
        ACT1[(size_t)t * G4 + r] = a;
      }
    }
    // gate exchange within wave: gates of unit u at lanes un, un+16, un+32, un+48
    float vf = __shfl_down(a, 16, 64);
    float vg = __shfl_down(a, 32, 64);
    float vo = __shfl_down(a, 48, 64);
    if (act && grp == 0) {
      cc = vf * cc + a * vg;
      float e2 = __expf(-2.0f * cc);
      float th = 2.0f / (1.0f + e2) - 1.0f;
      float h = vo * th;
      hbuf[wbuf][li][u] = h;
      if (!isL1) {
        H0S[(size_t)(s + 1) * HID + u] = h;
        C0S[(size_t)(s + 1) * HID + u] = cc;
      } else {
        H1S[(size_t)(t + 2) * HID + u] = h;
        C1S[(size_t)(t + 2) * HID + u] = cc;
      }
    }
    // one barrier per superstep; do NOT drain vmcnt (global stores fire-and-forget)
    asm volatile("s_waitcnt lgkmcnt(0)" ::: "memory");
    __builtin_amdgcn_sched_barrier(0);
    __builtin_amdgcn_s_barrier();
    __builtin_amdgcn_sched_barrier(0);
  }
}

// ---------------- per-t gradient (fully parallel; uses stored activations only) ----------------
__global__ __launch_bounds__(256) void wl_grad_kernel(const float* __restrict__ Wih0,
                                                      const float* __restrict__ Whh0,
                                                      const float* __restrict__ Wih1,
                                                      const float* __restrict__ Whh1,
                                                      float* __restrict__ ws) {
  int t = blockIdx.x;
  int tid = threadIdx.x;
  float* GOH = ws + OFF_GOH;
  float* GWS = ws + OFF_GWS;
  if (t == 0) {  // gohs[0]=0, gws[0]=0
    if (tid < HID) GOH[tid] = 0.0f;
    if (tid < DIN) GWS[tid] = 0.0f;
    return;
  }
  const float* ACT0 = ws + OFF_ACT0;
  const float* ACT1 = ws + OFF_ACT1;
  const float* C0S = ws + OFF_C0S;
  const float* C1S = ws + OFF_C1S;
  __shared__ float a3[G4], am[G4], a0[G4];
  __shared__ float dg3[G4], dg0[G4], dgm[G4];
  __shared__ float dh0n[HID], dh1m[HID], dc1m[HID];
  __shared__ float cbuf[5 * HID];  // c3 | c1m | c1pp | c0n | c0p
  __shared__ float wsum_s[HID];
  a3[tid] = ACT1[(size_t)t * G4 + tid];
  am[tid] = ACT1[(size_t)(t - 1) * G4 + tid];
  a0[tid] = ACT0[(size_t)t * G4 + tid];
  if (tid < HID) {
    cbuf[tid]           = C1S[(size_t)(t + 2) * HID + tid];  // c3  = c1[t]
    cbuf[HID + tid]     = C1S[(size_t)(t + 1) * HID + tid];  // c1m = c1[t-1]
    cbuf[2 * HID + tid] = C1S[(size_t)t * HID + tid];        // c1pp= c1[t-2]
    cbuf[3 * HID + tid] = C0S[(size_t)(t + 1) * HID + tid];  // c0n = c0[t]
    cbuf[4 * HID + tid] = C0S[(size_t)t * HID + tid];        // c0p = c0[t-1]
    wsum_s[tid] = ws[OFF_WSUM + tid];
  }
  __syncthreads();
  // backward through cell3 (== real layer-1 cell at step t)
  if (tid < HID) {
    int k = tid;
    float tc = tanh_(cbuf[k]);
    float si = a3[k], sf = a3[HID + k], tg = a3[2 * HID + k], so = a3[3 * HID + k];
    float dh = wsum_s[k];
    float dov = dh * tc * so * (1.0f - so);
    float dc = dh * so * (1.0f - tc * tc);
    dg3[k] = dc * tg * si * (1.0f - si);
    dg3[HID + k] = dc * cbuf[HID + k] * sf * (1.0f - sf);
    dg3[2 * HID + k] = dc * si * (1.0f - tg * tg);
    dg3[3 * HID + k] = dov;
    dc1m[k] = dc * sf;
  }
  __syncthreads();
  // dh0n = dg3 @ Wih1 ; dh1m = dg3 @ Whh1
  if (tid < HID) {
    float s = 0.0f;
#pragma unroll 8
    for (int j = 0; j < G4; ++j) s += dg3[j] * Wih1[(size_t)j * HID + tid];
    dh0n[tid] = s;
  } else if (tid < 2 * HID) {
    int k = tid - HID;
    float s = 0.0f;
#pragma unroll 8
    for (int j = 0; j < G4; ++j) s += dg3[j] * Whh1[(size_t)j * HID + k];
    dh1m[k] = s;
  }
  __syncthreads();
  // backward through cell0 (dc0n = 0) and cellm (== layer-1 cell at step t-1)
  if (tid < HID) {
    int k = tid;
    float tc = tanh_(cbuf[3 * HID + k]);
    float si = a0[k], sf = a0[HID + k], tg = a0[2 * HID + k], so = a0[3 * HID + k];
    float dh = dh0n[k];
    float dov = dh * tc * so * (1.0f - so);
    float dc = dh * so * (1.0f - tc * tc);
    dg0[k] = dc * tg * si * (1.0f - si);
    dg0[HID + k] = dc * cbuf[4 * HID + k] * sf * (1.0f - sf);
    dg0[2 * HID + k] = dc * si * (1.0f - tg * tg);
    dg0[3 * HID + k] = dov;
  } else if (tid < 2 * HID) {
    int k = tid - HID;
    float tc = tanh_(cbuf[HID + k]);
    float si = am[k], sf = am[HID + k], tg = am[2 * HID + k], so = am[3 * HID + k];
    float dh = dh1m[k];
    float dov = dh * tc * so * (1.0f - so);
    float dc = dh * so * (1.0f - tc * tc) + dc1m[k];
    dgm[k] = dc * tg * si * (1.0f - si);
    dgm[HID + k] = dc * cbuf[2 * HID + k] * sf * (1.0f - sf);
    dgm[2 * HID + k] = dc * si * (1.0f - tg * tg);
    dgm[3 * HID + k] = dov;
  }
  __syncthreads();
  // gws = dg0 @ Wih0 ; gohs = dg0 @ Whh0 + dgm @ Wih1
  if (tid < DIN) {
    float s = 0.0f;
#pragma unroll 8
    for (int j = 0; j < G4; ++j) s += dg0[j] * Wih0[(size_t)j * DIN + tid];
    GWS[(size_t)t * DIN + tid] = s;
  } else if (tid < DIN + HID) {
    int k = tid - DIN;
    float sA = 0.0f, sB = 0.0f;
#pragma unroll 8
    for (int j = 0; j < G4; ++j) {
      sA += dg0[j] * Whh0[(size_t)j * HID + k];
      sB += dgm[j] * Wih1[(size_t)j * HID + k];
    }
    GOH[(size_t)t * HID + k] = sA + sB;
  }
}

// ---------------- outs[t] = Wlin @ h1[t] + blin ----------------
__global__ __launch_bounds__(256) void wl_outs_kernel(const float* __restrict__ Wlin,
                                                      const float* __restrict__ blin,
                                                      const float* __restrict__ ws,
                                                      float* __restrict__ out) {
  int tloc = threadIdx.x >> 5, o = threadIdx.x & 31;
  int t = blockIdx.x * 8 + tloc;
  if (o < NOUT) {
    const float* h1 = ws + OFF_H1S + (size_t)(t + 2) * HID;
    const float* wr = Wlin + o * HID;
    float s = blin[o];
#pragma unroll 8
    for (int k = 0; k < HID; ++k) s += wr[k] * h1[k];
    out[(size_t)t * NOUT + o] = s;
  }
}

// ---------------- column-wise min/max partials for gohs (m=0) and old_hts (m=1) ----------------
__global__ __launch_bounds__(256) void wl_mm_partial_kernel(float* __restrict__ ws) {
  int m = blockIdx.y;
  int col = threadIdx.x & 63, rg = threadIdx.x >> 6;
  const float* src = ws + (m == 0 ? OFF_GOH : OFF_H0S);  // H0S rows 0..8191 == old_hts
  float mn = 3.4e38f, mx = -3.4e38f;
  int r0 = blockIdx.x * 128;
  for (int r = r0 + rg; r < r0 + 128; r += 4) {
    float v = src[(size_t)r * HID + col];
    mn = fminf(mn, v);
    mx = fmaxf(mx, v);
  }
  __shared__ float smn[256], smx[256];
  smn[threadIdx.x] = mn;
  smx[threadIdx.x] = mx;
  __syncthreads();
  if (threadIdx.x < 64) {
    float a = fminf(fminf(smn[col], smn[64 + col]), fminf(smn[128 + col], smn[192 + col]));
    float b = fmaxf(fmaxf(smx[col], smx[64 + col]), fmaxf(smx[128 + col], smx[192 + col]));
    ws[OFF_PMN + ((size_t)m * 64 + blockIdx.x) * 64 + col] = a;
    ws[OFF_PMX + ((size_t)m * 64 + blockIdx.x) * 64 + col] = b;
  }
}

__global__ __launch_bounds__(128) void wl_mm_final_kernel(float* __restrict__ ws) {
  int i = threadIdx.x;
  if (i < 128) {
    int m = i >> 6, col = i & 63;
    float mn = 3.4e38f, mx = -3.4e38f;
    for (int b = 0; b < 64; ++b) {
      mn = fminf(mn, ws[OFF_PMN + ((size_t)m * 64 + b) * 64 + col]);
      mx = fmaxf(mx, ws[OFF_PMX + ((size_t)m * 64 + b) * 64 + col]);
    }
    ws[OFF_MN + i] = mn;
    ws[OFF_INV + i] = 1.0f / (mx - mn + 1e-6f);
  }
}

// ---------------- final: output_data assembly + HPM fwd + F + AllF_x ----------------
__global__ __launch_bounds__(256) void wl_final_kernel(const float* __restrict__ input,
                                                       const float* __restrict__ Whpm1,
                                                       const float* __restrict__ bhpm1,
                                                       const float* __restrict__ Whpm2,
                                                       const float* __restrict__ bhpm2,
                                                       const float* __restrict__ ws,
                                                       float* __restrict__ out) {
  int t = blockIdx.x;
  int tid = threadIdx.x;
  __shared__ float od[DHPM];
  __shared__ float red[256];
  __shared__ float zb[4];
  const float* GOH = ws + OFF_GOH;
  const float* H0S = ws + OFF_H0S;
  const float* MNp = ws + OFF_MN;
  const float* INVp = ws + OFF_INV;
  if (tid < NOUT) {
    od[tid] = out[(size_t)t * NOUT + tid];
  } else if (tid < 74) {
    int k = tid - 10;
    od[tid] = (GOH[(size_t)t * HID + k] - MNp[k]) * INVp[k];
  } else if (tid < 194) {
    int q = tid - 74;
    od[tid] = input[(size_t)t * DIN + q];
  } else {
    int k = tid - 194;
    od[tid] = (H0S[(size_t)t * HID + k] - MNp[64 + k]) * INVp[64 + k];
  }
  if (tid < 2) {
    int k = 62 + tid;
    od[256 + tid] = (H0S[(size_t)t * HID + k] - MNp[64 + k]) * INVp[64 + k];
  }
  __syncthreads();
  // z1pre[0]
  float p = od[tid] * Whpm1[tid];
  if (tid < 2) p += od[256 + tid] * Whpm1[256 + tid];
  red[tid] = p;
  __syncthreads();
  for (int off = 128; off > 0; off >>= 1) {
    if (tid < off) red[tid] += red[tid + off];
    __syncthreads();
  }
  if (tid == 0) zb[0] = red[0];
  __syncthreads();
  // z1pre[1]
  p = od[tid] * Whpm1[DHPM + tid];
  if (tid < 2) p += od[256 + tid] * Whpm1[DHPM + 256 + tid];
  red[tid] = p;
  __syncthreads();
  for (int off = 128; off > 0; off >>= 1) {
    if (tid < off) red[tid] += red[tid + off];
    __syncthreads();
  }
  if (tid == 0) {
    float z0 = tanh_(zb[0] + bhpm1[0]);
    float z1 = tanh_(red[0] + bhpm1[1]);
    zb[0] = z0;
    zb[1] = z1;
    zb[2] = ws[OFF_S2 + 0] * (1.0f - z0 * z0);
    zb[3] = ws[OFF_S2 + 1] * (1.0f - z1 * z1);
  }
  __syncthreads();
  float z0 = zb[0], z1 = zb[1], d0 = zb[2], d1 = zb[3];
  if (tid < DIN) {
    float G = bhpm2[tid] + z0 * Whpm2[tid * 2] + z1 * Whpm2[tid * 2 + 1];
    out[(size_t)S_LEN * NOUT + (size_t)t * DIN + tid] = ws[OFF_GWS + (size_t)t * DIN + tid] - G;
  }
  out[(size_t)S_LEN * (NOUT + DIN) + (size_t)t * DHPM + tid] = -(d0 * Whpm1[tid] + d1 * Whpm1[DHPM + tid]);
  if (tid < 2) {
    int i2 = 256 + tid;
    out[(size_t)S_LEN * (NOUT + DIN) + (size_t)t * DHPM + i2] = -(d0 * Whpm1[i2] + d1 * Whpm1[DHPM + i2]);
  }
}

extern "C" void kernel_launch(void* const* d_in, const int* in_sizes, int n_in,
                              void* d_out, int out_size, void* d_ws, size_t ws_size,
                              hipStream_t stream) {
  const float* input = (const float*)d_in[0];
  const float* Wih0 = (const float*)d_in[1];
  const float* Whh0 = (const float*)d_in[2];
  const float* bih0 = (const float*)d_in[3];
  const float* bhh0 = (const float*)d_in[4];
  const float* Wih1 = (const float*)d_in[5];
  const float* Whh1 = (const float*)d_in[6];
  const float* bih1 = (const float*)d_in[7];
  const float* bhh1 = (const float*)d_in[8];
  const float* Wlin = (const float*)d_in[9];
  const float* blin = (const float*)d_in[10];
  const float* Whpm1 = (const float*)d_in[11];
  const float* bhpm1 = (const float*)d_in[12];
  const float* Whpm2 = (const float*)d_in[13];
  const float* bhpm2 = (const float*)d_in[14];
  float* ws = (float*)d_ws;
  float* out = (float*)d_out;

  wl_prep_kernel<<<1, 128, 0, stream>>>(Wlin, Whpm2, ws);
  wl_pre0_kernel<<<S_LEN / 8, 256, 0, stream>>>(input, Wih0, bih0, bhh0, ws);
  wl_scan_kernel<<<1, 512, 0, stream>>>(Whh0, Wih1, Whh1, bih1, bhh1, ws);
  wl_grad_kernel<<<S_LEN, 256, 0, stream>>>(Wih0, Whh0, Wih1, Whh1, ws);
  wl_outs_kernel<<<S_LEN / 8, 256, 0, stream>>>(Wlin, blin, ws, out);
  wl_mm_partial_kernel<<<dim3(64, 2), 256, 0, stream>>>(ws);
  wl_mm_final_kernel<<<1, 128, 0, stream>>>(ws);
  wl_final_kernel<<<S_LEN, 256, 0, stream>>>(input, Whpm1, bhpm1, Whpm2, bhpm2, ws, out);
}

// Round 3
// 8833.167 us; speedup vs baseline: 1.2907x; 1.2907x over previous
//
#include <hip/hip_runtime.h>

#define S_LEN 8192
#define DIN 120
#define HID 64
#define G4 256
#define NOUT 10
#define DHPM 258

// ---------------- workspace layout (float offsets) ----------------
static constexpr size_t OFF_PRE0 = 0;                                  // [S][256]
static constexpr size_t OFF_ACT0 = OFF_PRE0 + (size_t)S_LEN * G4;      // [S][256] activated gates L0
static constexpr size_t OFF_ACT1 = OFF_ACT0 + (size_t)S_LEN * G4;      // [S][256] activated gates L1
static constexpr size_t OFF_H0S  = OFF_ACT1 + (size_t)S_LEN * G4;      // [S+1][64]  row t+1 = h0 after step t, row0 = 0
static constexpr size_t OFF_C0S  = OFF_H0S + (size_t)(S_LEN + 1) * HID;
static constexpr size_t OFF_H1S  = OFF_C0S + (size_t)(S_LEN + 1) * HID; // [S+2][64] row t+2 = h1 after step t
static constexpr size_t OFF_C1S  = OFF_H1S + (size_t)(S_LEN + 2) * HID;
static constexpr size_t OFF_GOH  = OFF_C1S + (size_t)(S_LEN + 2) * HID; // [S][64]
static constexpr size_t OFF_GWS  = OFF_GOH + (size_t)S_LEN * HID;       // [S][120]
static constexpr size_t OFF_PMN  = OFF_GWS + (size_t)S_LEN * DIN;       // [2][64][64]
static constexpr size_t OFF_PMX  = OFF_PMN + 2 * 64 * 64;
static constexpr size_t OFF_MN   = OFF_PMX + 2 * 64 * 64;               // [2][64]
static constexpr size_t OFF_INV  = OFF_MN + 128;                        // [2][64]
static constexpr size_t OFF_WSUM = OFF_INV + 128;                       // [64]
static constexpr size_t OFF_S2   = OFF_WSUM + 64;                       // [2]

__device__ __forceinline__ float sig_(float x)  { return 1.0f / (1.0f + __expf(-x)); }
__device__ __forceinline__ float tanh_(float x) { return 1.0f - 2.0f / (__expf(2.0f * x) + 1.0f); }

// ---------------- prep: wsum = colsum(Wlin), s2 = colsum(Whpm2) ----------------
__global__ __launch_bounds__(128) void wl_prep_kernel(const float* __restrict__ Wlin,
                                                      const float* __restrict__ Whpm2,
                                                      float* __restrict__ ws) {
  int i = threadIdx.x;
  if (i < HID) {
    float s = 0.0f;
    for (int o = 0; o < NOUT; ++o) s += Wlin[o * HID + i];
    ws[OFF_WSUM + i] = s;
  } else if (i < HID + 2) {
    int h = i - HID;
    float s = 0.0f;
    for (int d = 0; d < DIN; ++d) s += Whpm2[d * 2 + h];
    ws[OFF_S2 + h] = s;
  }
}

// ---------------- pre0 = input @ Wih0.T + bih0 + bhh0 (8 timesteps per block) ----------------
__global__ __launch_bounds__(256) void wl_pre0_kernel(const float* __restrict__ input,
                                                      const float* __restrict__ Wih0,
                                                      const float* __restrict__ bih0,
                                                      const float* __restrict__ bhh0,
                                                      float* __restrict__ ws) {
  __shared__ __align__(16) float xin[8 * DIN];
  int tid = threadIdx.x;
  size_t t0 = (size_t)blockIdx.x * 8;
  for (int idx = tid; idx < 8 * DIN; idx += 256) xin[idx] = input[t0 * DIN + idx];
  float4 w[30];
  const float4* wr = (const float4*)(Wih0 + (size_t)tid * DIN);
#pragma unroll
  for (int i = 0; i < 30; ++i) w[i] = wr[i];
  float b = bih0[tid] + bhh0[tid];
  __syncthreads();
#pragma unroll
  for (int tt = 0; tt < 8; ++tt) {
    const float4* x4 = (const float4*)(xin + tt * DIN);
    float acc = b;
#pragma unroll
    for (int i = 0; i < 30; ++i) {
      float4 x = x4[i];
      acc += w[i].x * x.x + w[i].y * x.y + w[i].z * x.z + w[i].w * x.w;
    }
    ws[OFF_PRE0 + (t0 + tt) * G4 + tid] = acc;
  }
}

// ---------------- sequential scan: 4 waves, merged L0+L1 per lane ----------------
// 256 threads. Lane tid computes gate row tid of layer0 AND gate row tid of
// layer1 (lagged one superstep: at superstep s, L0 produces gates for t=s
// using h0[s-1]; L1 produces gates for t=s-1 using h0[s-1] and h1[s-2] --
// the SAME h0 vector, read once per lane). Gate exchange via a0/a1 LDS
// (stride-1, conflict-free). Cell update: lanes 0-63 own (h0,c0), lanes
// 64-127 own (h1,c1), c register-resident. Raw s_barrier with lgkmcnt-only
// waits: global stores of ACT/H/C are fire-and-forget (no vmcnt drain).
__global__ __launch_bounds__(256, 1) void wl_scan_kernel(const float* __restrict__ Whh0,
                                                         const float* __restrict__ Wih1,
                                                         const float* __restrict__ Whh1,
                                                         const float* __restrict__ bih1,
                                                         const float* __restrict__ bhh1,
                                                         float* __restrict__ ws) {
  __shared__ __align__(16) float hbuf[2][2][HID];  // [buf][layer][unit]
  __shared__ float a0_lds[G4];
  __shared__ float a1_lds[G4];
  float* ACT0 = ws + OFF_ACT0;
  float* ACT1 = ws + OFF_ACT1;
  float* H0S = ws + OFF_H0S;
  float* C0S = ws + OFF_C0S;
  float* H1S = ws + OFF_H1S;
  float* C1S = ws + OFF_C1S;
  const float* PRE0 = ws + OFF_PRE0;

  int tid = threadIdx.x;
  int grp = tid >> 6;  // gate: 0=i 1=f 2=g(tanh) 3=o
  int u = tid & 63;

  // activation constants: grp==2 -> tanh(x)=2/(1+e^{-2x})-1 ; else sigmoid
  float m = (grp == 2) ? -2.0f : -1.0f;
  float fa = (grp == 2) ? 2.0f : 1.0f;
  float fb = (grp == 2) ? -1.0f : 0.0f;

  float4 w0[16], wi1[16], wh1[16];
  {
    const float4* W0 = (const float4*)(Whh0 + (size_t)tid * HID);
    const float4* Wi = (const float4*)(Wih1 + (size_t)tid * HID);
    const float4* Wh = (const float4*)(Whh1 + (size_t)tid * HID);
#pragma unroll
    for (int i = 0; i < 16; ++i) { w0[i] = W0[i]; wi1[i] = Wi[i]; wh1[i] = Wh[i]; }
  }
  float b1 = bih1[tid] + bhh1[tid];

  // init LDS h buffers and boundary rows of the global state arrays
  ((float*)hbuf)[tid] = 0.0f;
  if (tid < HID) {
    H0S[tid] = 0.0f; C0S[tid] = 0.0f;
    H1S[tid] = 0.0f; H1S[HID + tid] = 0.0f;
    C1S[tid] = 0.0f; C1S[HID + tid] = 0.0f;
  }
  float cc = 0.0f;
  float pre_n = PRE0[tid];
  __syncthreads();

  for (int s = 0; s <= S_LEN; ++s) {
    int rb = s & 1, wb = rb ^ 1;
    const float4* h04 = (const float4*)hbuf[rb][0];
    const float4* h14 = (const float4*)hbuf[rb][1];
    // both matvecs share the h0 loads; 12 independent FMA chains of depth 16
    float4 sA = make_float4(0.f, 0.f, 0.f, 0.f);  // w0  . h0
    float4 sB = make_float4(0.f, 0.f, 0.f, 0.f);  // wi1 . h0
    float4 sC = make_float4(0.f, 0.f, 0.f, 0.f);  // wh1 . h1
#pragma unroll
    for (int i = 0; i < 16; ++i) {
      float4 h0v = h04[i];
      float4 h1v = h14[i];
      sA.x += w0[i].x * h0v.x;  sA.y += w0[i].y * h0v.y;
      sA.z += w0[i].z * h0v.z;  sA.w += w0[i].w * h0v.w;
      sB.x += wi1[i].x * h0v.x; sB.y += wi1[i].y * h0v.y;
      sB.z += wi1[i].z * h0v.z; sB.w += wi1[i].w * h0v.w;
      sC.x += wh1[i].x * h1v.x; sC.y += wh1[i].y * h1v.y;
      sC.z += wh1[i].z * h1v.z; sC.w += wh1[i].w * h1v.w;
    }
    if (s < S_LEN) {
      float g0 = pre_n + (sA.x + sA.y) + (sA.z + sA.w);
      if (s + 1 < S_LEN) pre_n = PRE0[(size_t)(s + 1) * G4 + tid];  // prefetch
      float e = __expf(m * g0);
      float a = fa / (1.0f + e) + fb;
      a0_lds[tid] = a;
      ACT0[(size_t)s * G4 + tid] = a;
    }
    if (s >= 1) {
      int t = s - 1;
      float g1 = b1 + (sB.x + sB.y) + (sB.z + sB.w) + (sC.x + sC.y) + (sC.z + sC.w);
      float e = __expf(m * g1);
      float a = fa / (1.0f + e) + fb;
      a1_lds[tid] = a;
      ACT1[(size_t)t * G4 + tid] = a;
    }
    asm volatile("s_waitcnt lgkmcnt(0)" ::: "memory");
    __builtin_amdgcn_sched_barrier(0);
    __builtin_amdgcn_s_barrier();
    __builtin_amdgcn_sched_barrier(0);
    // cell phase: wave 0 -> (h0,c0), wave 1 -> (h1,c1)
    if (tid < HID) {
      if (s < S_LEN) {
        float i_ = a0_lds[u], f_ = a0_lds[HID + u], g_ = a0_lds[2 * HID + u], o_ = a0_lds[3 * HID + u];
        cc = f_ * cc + i_ * g_;
        float e2 = __expf(-2.0f * cc);
        float th = 2.0f / (1.0f + e2) - 1.0f;
        float h = o_ * th;
        hbuf[wb][0][u] = h;
        H0S[(size_t)(s + 1) * HID + u] = h;
        C0S[(size_t)(s + 1) * HID + u] = cc;
      }
    } else if (tid < 2 * HID) {
      if (s >= 1) {
        int t = s - 1;
        float i_ = a1_lds[u], f_ = a1_lds[HID + u], g_ = a1_lds[2 * HID + u], o_ = a1_lds[3 * HID + u];
        cc = f_ * cc + i_ * g_;
        float e2 = __expf(-2.0f * cc);
        float th = 2.0f / (1.0f + e2) - 1.0f;
        float h = o_ * th;
        hbuf[wb][1][u] = h;
        H1S[(size_t)(t + 2) * HID + u] = h;
        C1S[(size_t)(t + 2) * HID + u] = cc;
      }
    }
    asm volatile("s_waitcnt lgkmcnt(0)" ::: "memory");
    __builtin_amdgcn_sched_barrier(0);
    __builtin_amdgcn_s_barrier();
    __builtin_amdgcn_sched_barrier(0);
  }
}

// ---------------- per-t gradient (fully parallel; uses stored activations only) ----------------
__global__ __launch_bounds__(256) void wl_grad_kernel(const float* __restrict__ Wih0,
                                                      const float* __restrict__ Whh0,
                                                      const float* __restrict__ Wih1,
                                                      const float* __restrict__ Whh1,
                                                      float* __restrict__ ws) {
  int t = blockIdx.x;
  int tid = threadIdx.x;
  float* GOH = ws + OFF_GOH;
  float* GWS = ws + OFF_GWS;
  if (t == 0) {  // gohs[0]=0, gws[0]=0
    if (tid < HID) GOH[tid] = 0.0f;
    if (tid < DIN) GWS[tid] = 0.0f;
    return;
  }
  const float* ACT0 = ws + OFF_ACT0;
  const float* ACT1 = ws + OFF_ACT1;
  const float* C0S = ws + OFF_C0S;
  const float* C1S = ws + OFF_C1S;
  __shared__ float a3[G4], am[G4], a0[G4];
  __shared__ float dg3[G4], dg0[G4], dgm[G4];
  __shared__ float dh0n[HID], dh1m[HID], dc1m[HID];
  __shared__ float cbuf[5 * HID];  // c3 | c1m | c1pp | c0n | c0p
  __shared__ float wsum_s[HID];
  a3[tid] = ACT1[(size_t)t * G4 + tid];
  am[tid] = ACT1[(size_t)(t - 1) * G4 + tid];
  a0[tid] = ACT0[(size_t)t * G4 + tid];
  if (tid < HID) {
    cbuf[tid]           = C1S[(size_t)(t + 2) * HID + tid];  // c3  = c1[t]
    cbuf[HID + tid]     = C1S[(size_t)(t + 1) * HID + tid];  // c1m = c1[t-1]
    cbuf[2 * HID + tid] = C1S[(size_t)t * HID + tid];        // c1pp= c1[t-2]
    cbuf[3 * HID + tid] = C0S[(size_t)(t + 1) * HID + tid];  // c0n = c0[t]
    cbuf[4 * HID + tid] = C0S[(size_t)t * HID + tid];        // c0p = c0[t-1]
    wsum_s[tid] = ws[OFF_WSUM + tid];
  }
  __syncthreads();
  // backward through cell3 (== real layer-1 cell at step t)
  if (tid < HID) {
    int k = tid;
    float tc = tanh_(cbuf[k]);
    float si = a3[k], sf = a3[HID + k], tg = a3[2 * HID + k], so = a3[3 * HID + k];
    float dh = wsum_s[k];
    float dov = dh * tc * so * (1.0f - so);
    float dc = dh * so * (1.0f - tc * tc);
    dg3[k] = dc * tg * si * (1.0f - si);
    dg3[HID + k] = dc * cbuf[HID + k] * sf * (1.0f - sf);
    dg3[2 * HID + k] = dc * si * (1.0f - tg * tg);
    dg3[3 * HID + k] = dov;
    dc1m[k] = dc * sf;
  }
  __syncthreads();
  // dh0n = dg3 @ Wih1 ; dh1m = dg3 @ Whh1
  if (tid < HID) {
    float s = 0.0f;
#pragma unroll 8
    for (int j = 0; j < G4; ++j) s += dg3[j] * Wih1[(size_t)j * HID + tid];
    dh0n[tid] = s;
  } else if (tid < 2 * HID) {
    int k = tid - HID;
    float s = 0.0f;
#pragma unroll 8
    for (int j = 0; j < G4; ++j) s += dg3[j] * Whh1[(size_t)j * HID + k];
    dh1m[k] = s;
  }
  __syncthreads();
  // backward through cell0 (dc0n = 0) and cellm (== layer-1 cell at step t-1)
  if (tid < HID) {
    int k = tid;
    float tc = tanh_(cbuf[3 * HID + k]);
    float si = a0[k], sf = a0[HID + k], tg = a0[2 * HID + k], so = a0[3 * HID + k];
    float dh = dh0n[k];
    float dov = dh * tc * so * (1.0f - so);
    float dc = dh * so * (1.0f - tc * tc);
    dg0[k] = dc * tg * si * (1.0f - si);
    dg0[HID + k] = dc * cbuf[4 * HID + k] * sf * (1.0f - sf);
    dg0[2 * HID + k] = dc * si * (1.0f - tg * tg);
    dg0[3 * HID + k] = dov;
  } else if (tid < 2 * HID) {
    int k = tid - HID;
    float tc = tanh_(cbuf[HID + k]);
    float si = am[k], sf = am[HID + k], tg = am[2 * HID + k], so = am[3 * HID + k];
    float dh = dh1m[k];
    float dov = dh * tc * so * (1.0f - so);
    float dc = dh * so * (1.0f - tc * tc) + dc1m[k];
    dgm[k] = dc * tg * si * (1.0f - si);
    dgm[HID + k] = dc * cbuf[2 * HID + k] * sf * (1.0f - sf);
    dgm[2 * HID + k] = dc * si * (1.0f - tg * tg);
    dgm[3 * HID + k] = dov;
  }
  __syncthreads();
  // gws = dg0 @ Wih0 ; gohs = dg0 @ Whh0 + dgm @ Wih1
  if (tid < DIN) {
    float s = 0.0f;
#pragma unroll 8
    for (int j = 0; j < G4; ++j) s += dg0[j] * Wih0[(size_t)j * DIN + tid];
    GWS[(size_t)t * DIN + tid] = s;
  } else if (tid < DIN + HID) {
    int k = tid - DIN;
    float sA = 0.0f, sB = 0.0f;
#pragma unroll 8
    for (int j = 0; j < G4; ++j) {
      sA += dg0[j] * Whh0[(size_t)j * HID + k];
      sB += dgm[j] * Wih1[(size_t)j * HID + k];
    }
    GOH[(size_t)t * HID + k] = sA + sB;
  }
}

// ---------------- outs[t] = Wlin @ h1[t] + blin ----------------
__global__ __launch_bounds__(256) void wl_outs_kernel(const float* __restrict__ Wlin,
                                                      const float* __restrict__ blin,
                                                      const float* __restrict__ ws,
                                                      float* __restrict__ out) {
  int tloc = threadIdx.x >> 5, o = threadIdx.x & 31;
  int t = blockIdx.x * 8 + tloc;
  if (o < NOUT) {
    const float* h1 = ws + OFF_H1S + (size_t)(t + 2) * HID;
    const float* wr = Wlin + o * HID;
    float s = blin[o];
#pragma unroll 8
    for (int k = 0; k < HID; ++k) s += wr[k] * h1[k];
    out[(size_t)t * NOUT + o] = s;
  }
}

// ---------------- column-wise min/max partials for gohs (m=0) and old_hts (m=1) ----------------
__global__ __launch_bounds__(256) void wl_mm_partial_kernel(float* __restrict__ ws) {
  int m = blockIdx.y;
  int col = threadIdx.x & 63, rg = threadIdx.x >> 6;
  const float* src = ws + (m == 0 ? OFF_GOH : OFF_H0S);  // H0S rows 0..8191 == old_hts
  float mn = 3.4e38f, mx = -3.4e38f;
  int r0 = blockIdx.x * 128;
  for (int r = r0 + rg; r < r0 + 128; r += 4) {
    float v = src[(size_t)r * HID + col];
    mn = fminf(mn, v);
    mx = fmaxf(mx, v);
  }
  __shared__ float smn[256], smx[256];
  smn[threadIdx.x] = mn;
  smx[threadIdx.x] = mx;
  __syncthreads();
  if (threadIdx.x < 64) {
    float a = fminf(fminf(smn[col], smn[64 + col]), fminf(smn[128 + col], smn[192 + col]));
    float b = fmaxf(fmaxf(smx[col], smx[64 + col]), fmaxf(smx[128 + col], smx[192 + col]));
    ws[OFF_PMN + ((size_t)m * 64 + blockIdx.x) * 64 + col] = a;
    ws[OFF_PMX + ((size_t)m * 64 + blockIdx.x) * 64 + col] = b;
  }
}

__global__ __launch_bounds__(128) void wl_mm_final_kernel(float* __restrict__ ws) {
  int i = threadIdx.x;
  if (i < 128) {
    int m = i >> 6, col = i & 63;
    float mn = 3.4e38f, mx = -3.4e38f;
    for (int b = 0; b < 64; ++b) {
      mn = fminf(mn, ws[OFF_PMN + ((size_t)m * 64 + b) * 64 + col]);
      mx = fmaxf(mx, ws[OFF_PMX + ((size_t)m * 64 + b) * 64 + col]);
    }
    ws[OFF_MN + i] = mn;
    ws[OFF_INV + i] = 1.0f / (mx - mn + 1e-6f);
  }
}

// ---------------- final: output_data assembly + HPM fwd + F + AllF_x ----------------
__global__ __launch_bounds__(256) void wl_final_kernel(const float* __restrict__ input,
                                                       const float* __restrict__ Whpm1,
                                                       const float* __restrict__ bhpm1,
                                                       const float* __restrict__ Whpm2,
                                                       const float* __restrict__ bhpm2,
                                                       const float* __restrict__ ws,
                                                       float* __restrict__ out) {
  int t = blockIdx.x;
  int tid = threadIdx.x;
  __shared__ float od[DHPM];
  __shared__ float red[256];
  __shared__ float zb[4];
  const float* GOH = ws + OFF_GOH;
  const float* H0S = ws + OFF_H0S;
  const float* MNp = ws + OFF_MN;
  const float* INVp = ws + OFF_INV;
  if (tid < NOUT) {
    od[tid] = out[(size_t)t * NOUT + tid];
  } else if (tid < 74) {
    int k = tid - 10;
    od[tid] = (GOH[(size_t)t * HID + k] - MNp[k]) * INVp[k];
  } else if (tid < 194) {
    int q = tid - 74;
    od[tid] = input[(size_t)t * DIN + q];
  } else {
    int k = tid - 194;
    od[tid] = (H0S[(size_t)t * HID + k] - MNp[64 + k]) * INVp[64 + k];
  }
  if (tid < 2) {
    int k = 62 + tid;
    od[256 + tid] = (H0S[(size_t)t * HID + k] - MNp[64 + k]) * INVp[64 + k];
  }
  __syncthreads();
  // z1pre[0]
  float p = od[tid] * Whpm1[tid];
  if (tid < 2) p += od[256 + tid] * Whpm1[256 + tid];
  red[tid] = p;
  __syncthreads();
  for (int off = 128; off > 0; off >>= 1) {
    if (tid < off) red[tid] += red[tid + off];
    __syncthreads();
  }
  if (tid == 0) zb[0] = red[0];
  __syncthreads();
  // z1pre[1]
  p = od[tid] * Whpm1[DHPM + tid];
  if (tid < 2) p += od[256 + tid] * Whpm1[DHPM + 256 + tid];
  red[tid] = p;
  __syncthreads();
  for (int off = 128; off > 0; off >>= 1) {
    if (tid < off) red[tid] += red[tid + off];
    __syncthreads();
  }
  if (tid == 0) {
    float z0 = tanh_(zb[0] + bhpm1[0]);
    float z1 = tanh_(red[0] + bhpm1[1]);
    zb[0] = z0;
    zb[1] = z1;
    zb[2] = ws[OFF_S2 + 0] * (1.0f - z0 * z0);
    zb[3] = ws[OFF_S2 + 1] * (1.0f - z1 * z1);
  }
  __syncthreads();
  float z0 = zb[0], z1 = zb[1], d0 = zb[2], d1 = zb[3];
  if (tid < DIN) {
    float G = bhpm2[tid] + z0 * Whpm2[tid * 2] + z1 * Whpm2[tid * 2 + 1];
    out[(size_t)S_LEN * NOUT + (size_t)t * DIN + tid] = ws[OFF_GWS + (size_t)t * DIN + tid] - G;
  }
  out[(size_t)S_LEN * (NOUT + DIN) + (size_t)t * DHPM + tid] = -(d0 * Whpm1[tid] + d1 * Whpm1[DHPM + tid]);
  if (tid < 2) {
    int i2 = 256 + tid;
    out[(size_t)S_LEN * (NOUT + DIN) + (size_t)t * DHPM + i2] = -(d0 * Whpm1[i2] + d1 * Whpm1[DHPM + i2]);
  }
}

extern "C" void kernel_launch(void* const* d_in, const int* in_sizes, int n_in,
                              void* d_out, int out_size, void* d_ws, size_t ws_size,
                              hipStream_t stream) {
  const float* input = (const float*)d_in[0];
  const float* Wih0 = (const float*)d_in[1];
  const float* Whh0 = (const float*)d_in[2];
  const float* bih0 = (const float*)d_in[3];
  const float* bhh0 = (const float*)d_in[4];
  const float* Wih1 = (const float*)d_in[5];
  const float* Whh1 = (const float*)d_in[6];
  const float* bih1 = (const float*)d_in[7];
  const float* bhh1 = (const float*)d_in[8];
  const float* Wlin = (const float*)d_in[9];
  const float* blin = (const float*)d_in[10];
  const float* Whpm1 = (const float*)d_in[11];
  const float* bhpm1 = (const float*)d_in[12];
  const float* Whpm2 = (const float*)d_in[13];
  const float* bhpm2 = (const float*)d_in[14];
  float* ws = (float*)d_ws;
  float* out = (float*)d_out;

  wl_prep_kernel<<<1, 128, 0, stream>>>(Wlin, Whpm2, ws);
  wl_pre0_kernel<<<S_LEN / 8, 256, 0, stream>>>(input, Wih0, bih0, bhh0, ws);
  wl_scan_kernel<<<1, 256, 0, stream>>>(Whh0, Wih1, Whh1, bih1, bhh1, ws);
  wl_grad_kernel<<<S_LEN, 256, 0, stream>>>(Wih0, Whh0, Wih1, Whh1, ws);
  wl_outs_kernel<<<S_LEN / 8, 256, 0, stream>>>(Wlin, blin, ws, out);
  wl_mm_partial_kernel<<<dim3(64, 2), 256, 0, stream>>>(ws);
  wl_mm_final_kernel<<<1, 128, 0, stream>>>(ws);
  wl_final_kernel<<<S_LEN, 256, 0, stream>>>(input, Whpm1, bhpm1, Whpm2, bhpm2, ws, out);
}

// Round 4
// 6174.487 us; speedup vs baseline: 1.8464x; 1.4306x over previous
//
#include <hip/hip_runtime.h>

#define S_LEN 8192
#define DIN 120
#define HID 64
#define G4 256
#define NOUT 10
#define DHPM 258

typedef _Float16 h2 __attribute__((ext_vector_type(2)));
typedef _Float16 h8 __attribute__((ext_vector_type(8)));

#if __has_builtin(__builtin_amdgcn_fdot2)
#define FDOT2(a, b, c) __builtin_amdgcn_fdot2((a), (b), (c), false)
#else
static __device__ __forceinline__ float FDOT2(h2 a, h2 b, float c) {
  float r = c;
  asm("v_dot2_f32_f16 %0, %1, %2, %0" : "+v"(r) : "v"(a), "v"(b));
  return r;
}
#endif

// ---------------- workspace layout (float offsets) ----------------
static constexpr size_t OFF_PRE0 = 0;                                  // [S][256]
static constexpr size_t OFF_ACT0 = OFF_PRE0 + (size_t)S_LEN * G4;      // [S][256] activated gates L0
static constexpr size_t OFF_ACT1 = OFF_ACT0 + (size_t)S_LEN * G4;      // [S][256] activated gates L1
static constexpr size_t OFF_H0S  = OFF_ACT1 + (size_t)S_LEN * G4;      // [S+1][64]  row t+1 = h0 after step t, row0 = 0
static constexpr size_t OFF_C0S  = OFF_H0S + (size_t)(S_LEN + 1) * HID;
static constexpr size_t OFF_H1S  = OFF_C0S + (size_t)(S_LEN + 1) * HID; // [S+2][64] row t+2 = h1 after step t
static constexpr size_t OFF_C1S  = OFF_H1S + (size_t)(S_LEN + 2) * HID;
static constexpr size_t OFF_GOH  = OFF_C1S + (size_t)(S_LEN + 2) * HID; // [S][64]
static constexpr size_t OFF_GWS  = OFF_GOH + (size_t)S_LEN * HID;       // [S][120]
static constexpr size_t OFF_PMN  = OFF_GWS + (size_t)S_LEN * DIN;       // [2][64][64]
static constexpr size_t OFF_PMX  = OFF_PMN + 2 * 64 * 64;
static constexpr size_t OFF_MN   = OFF_PMX + 2 * 64 * 64;               // [2][64]
static constexpr size_t OFF_INV  = OFF_MN + 128;                        // [2][64]
static constexpr size_t OFF_WSUM = OFF_INV + 128;                       // [64]
static constexpr size_t OFF_S2   = OFF_WSUM + 64;                       // [2]

__device__ __forceinline__ float sig_(float x)  { return 1.0f / (1.0f + __expf(-x)); }
__device__ __forceinline__ float tanh_(float x) { return 1.0f - 2.0f / (__expf(2.0f * x) + 1.0f); }

// ---------------- prep: wsum = colsum(Wlin), s2 = colsum(Whpm2) ----------------
__global__ __launch_bounds__(128) void wl_prep_kernel(const float* __restrict__ Wlin,
                                                      const float* __restrict__ Whpm2,
                                                      float* __restrict__ ws) {
  int i = threadIdx.x;
  if (i < HID) {
    float s = 0.0f;
    for (int o = 0; o < NOUT; ++o) s += Wlin[o * HID + i];
    ws[OFF_WSUM + i] = s;
  } else if (i < HID + 2) {
    int h = i - HID;
    float s = 0.0f;
    for (int d = 0; d < DIN; ++d) s += Whpm2[d * 2 + h];
    ws[OFF_S2 + h] = s;
  }
}

// ---------------- pre0 = input @ Wih0.T + bih0 + bhh0 (8 timesteps per block) ----------------
__global__ __launch_bounds__(256) void wl_pre0_kernel(const float* __restrict__ input,
                                                      const float* __restrict__ Wih0,
                                                      const float* __restrict__ bih0,
                                                      const float* __restrict__ bhh0,
                                                      float* __restrict__ ws) {
  __shared__ __align__(16) float xin[8 * DIN];
  int tid = threadIdx.x;
  size_t t0 = (size_t)blockIdx.x * 8;
  for (int idx = tid; idx < 8 * DIN; idx += 256) xin[idx] = input[t0 * DIN + idx];
  float4 w[30];
  const float4* wr = (const float4*)(Wih0 + (size_t)tid * DIN);
#pragma unroll
  for (int i = 0; i < 30; ++i) w[i] = wr[i];
  float b = bih0[tid] + bhh0[tid];
  __syncthreads();
#pragma unroll
  for (int tt = 0; tt < 8; ++tt) {
    const float4* x4 = (const float4*)(xin + tt * DIN);
    float acc = b;
#pragma unroll
    for (int i = 0; i < 30; ++i) {
      float4 x = x4[i];
      acc += w[i].x * x.x + w[i].y * x.y + w[i].z * x.z + w[i].w * x.w;
    }
    ws[OFF_PRE0 + (t0 + tt) * G4 + tid] = acc;
  }
}

// ---------------- sequential scan: 512 thr / 8 waves; h broadcast in f16, dot2 matvec ----------------
// Waves 0-3 (tid<256): layer0 gate rows, r=tid. Waves 4-7: layer1 gate rows, r=tid-256,
// lagging one superstep. h0/h1 live in LDS as packed f16 (128B each) -> 8 ds_read_b128
// per lane-row instead of 16 f32 reads. Gate exchange via f32 a0/a1 LDS; cell state
// register-resident in wave 0 (L0) / wave 4 (L1). Light barriers: lgkmcnt-only drain,
// global stores of ACT/H/C are fire-and-forget.
__global__ __launch_bounds__(512, 1) void wl_scan_kernel(const float* __restrict__ Whh0,
                                                         const float* __restrict__ Wih1,
                                                         const float* __restrict__ Whh1,
                                                         const float* __restrict__ bih1,
                                                         const float* __restrict__ bhh1,
                                                         float* __restrict__ ws) {
  __shared__ __align__(16) h8 h0h[2][8];   // [buf][64 halves]
  __shared__ __align__(16) h8 h1h[2][8];
  __shared__ float a0_lds[G4];
  __shared__ float a1_lds[G4];
  float* ACT0 = ws + OFF_ACT0;
  float* ACT1 = ws + OFF_ACT1;
  float* H0S = ws + OFF_H0S;
  float* C0S = ws + OFF_C0S;
  float* H1S = ws + OFF_H1S;
  float* C1S = ws + OFF_C1S;
  const float* PRE0 = ws + OFF_PRE0;

  int tid = threadIdx.x;
  bool isL1 = (tid >= G4);
  int r = isL1 ? (tid - G4) : tid;
  int grp = r >> 6;  // 0=i 1=f 2=g(tanh) 3=o

  // activation constants: grp==2 -> tanh(x)=2/(1+e^{-2x})-1 ; else sigmoid
  float m = (grp == 2) ? -2.0f : -1.0f;
  float fa = (grp == 2) ? 2.0f : 1.0f;
  float fb = (grp == 2) ? -1.0f : 0.0f;

  // convert weight rows to f16 (h8 = 8 halves = 16B = 4 VGPR each)
  h8 wA[8], wB[8];
  float b1 = 0.0f;
  if (!isL1) {
    const float4* W = (const float4*)(Whh0 + (size_t)r * HID);
#pragma unroll
    for (int i = 0; i < 8; ++i) {
      float4 x = W[2 * i], y = W[2 * i + 1];
      wA[i][0] = (_Float16)x.x; wA[i][1] = (_Float16)x.y;
      wA[i][2] = (_Float16)x.z; wA[i][3] = (_Float16)x.w;
      wA[i][4] = (_Float16)y.x; wA[i][5] = (_Float16)y.y;
      wA[i][6] = (_Float16)y.z; wA[i][7] = (_Float16)y.w;
    }
  } else {
    const float4* Wi = (const float4*)(Wih1 + (size_t)r * HID);
    const float4* Wh = (const float4*)(Whh1 + (size_t)r * HID);
#pragma unroll
    for (int i = 0; i < 8; ++i) {
      float4 x = Wi[2 * i], y = Wi[2 * i + 1];
      wA[i][0] = (_Float16)x.x; wA[i][1] = (_Float16)x.y;
      wA[i][2] = (_Float16)x.z; wA[i][3] = (_Float16)x.w;
      wA[i][4] = (_Float16)y.x; wA[i][5] = (_Float16)y.y;
      wA[i][6] = (_Float16)y.z; wA[i][7] = (_Float16)y.w;
      x = Wh[2 * i]; y = Wh[2 * i + 1];
      wB[i][0] = (_Float16)x.x; wB[i][1] = (_Float16)x.y;
      wB[i][2] = (_Float16)x.z; wB[i][3] = (_Float16)x.w;
      wB[i][4] = (_Float16)y.x; wB[i][5] = (_Float16)y.y;
      wB[i][6] = (_Float16)y.z; wB[i][7] = (_Float16)y.w;
    }
    b1 = bih1[r] + bhh1[r];
  }

  // init LDS h buffers and boundary rows of the global state arrays
  if (tid < 128) {
    ((_Float16*)h0h)[tid] = (_Float16)0;
    ((_Float16*)h1h)[tid] = (_Float16)0;
  }
  if (tid < HID) {
    H0S[tid] = 0.0f; C0S[tid] = 0.0f;
    H1S[tid] = 0.0f; H1S[HID + tid] = 0.0f;
    C1S[tid] = 0.0f; C1S[HID + tid] = 0.0f;
  }
  float cc = 0.0f;
  float pre_n = (!isL1) ? PRE0[tid] : 0.0f;
  __syncthreads();

  for (int s = 0; s <= S_LEN; ++s) {
    int rb = s & 1, wb = rb ^ 1;
    if (!isL1) {
      if (s < S_LEN) {
        const h8* hv = h0h[rb];
        float q0 = 0.f, q1 = 0.f, q2 = 0.f, q3 = 0.f;
#pragma unroll
        for (int i = 0; i < 8; ++i) {
          h8 hh = hv[i];
          h8 ww = wA[i];
          h2 ha = {hh[0], hh[1]}, hb = {hh[2], hh[3]}, hc = {hh[4], hh[5]}, hd = {hh[6], hh[7]};
          h2 wa = {ww[0], ww[1]}, wwb = {ww[2], ww[3]}, wc = {ww[4], ww[5]}, wd = {ww[6], ww[7]};
          q0 = FDOT2(wa, ha, q0);
          q1 = FDOT2(wwb, hb, q1);
          q2 = FDOT2(wc, hc, q2);
          q3 = FDOT2(wd, hd, q3);
        }
        float g0 = pre_n + (q0 + q1) + (q2 + q3);
        if (s + 1 < S_LEN) pre_n = PRE0[(size_t)(s + 1) * G4 + tid];  // prefetch
        float e = __expf(m * g0);
        float a = fa / (1.0f + e) + fb;
        a0_lds[r] = a;
        ACT0[(size_t)s * G4 + r] = a;
      }
    } else {
      if (s >= 1) {
        int t = s - 1;
        const h8* hv = h0h[rb];  // h0[t]
        const h8* gv = h1h[rb];  // h1[t-1]
        float q0 = 0.f, q1 = 0.f, q2 = 0.f, q3 = 0.f;
        float p0 = 0.f, p1 = 0.f, p2 = 0.f, p3 = 0.f;
#pragma unroll
        for (int i = 0; i < 8; ++i) {
          h8 hh = hv[i];
          h8 gg = gv[i];
          h8 wi = wA[i];
          h8 wh = wB[i];
          h2 ha = {hh[0], hh[1]}, hb = {hh[2], hh[3]}, hc = {hh[4], hh[5]}, hd = {hh[6], hh[7]};
          h2 ga = {gg[0], gg[1]}, gb = {gg[2], gg[3]}, gc = {gg[4], gg[5]}, gd = {gg[6], gg[7]};
          h2 ia = {wi[0], wi[1]}, ib = {wi[2], wi[3]}, ic = {wi[4], wi[5]}, id = {wi[6], wi[7]};
          h2 ka = {wh[0], wh[1]}, kb = {wh[2], wh[3]}, kc = {wh[4], wh[5]}, kd = {wh[6], wh[7]};
          q0 = FDOT2(ia, ha, q0);
          q1 = FDOT2(ib, hb, q1);
          q2 = FDOT2(ic, hc, q2);
          q3 = FDOT2(id, hd, q3);
          p0 = FDOT2(ka, ga, p0);
          p1 = FDOT2(kb, gb, p1);
          p2 = FDOT2(kc, gc, p2);
          p3 = FDOT2(kd, gd, p3);
        }
        float g1 = b1 + ((q0 + q1) + (q2 + q3)) + ((p0 + p1) + (p2 + p3));
        float e = __expf(m * g1);
        float a = fa / (1.0f + e) + fb;
        a1_lds[r] = a;
        ACT1[(size_t)t * G4 + r] = a;
      }
    }
    asm volatile("s_waitcnt lgkmcnt(0)" ::: "memory");
    __builtin_amdgcn_sched_barrier(0);
    __builtin_amdgcn_s_barrier();
    __builtin_amdgcn_sched_barrier(0);
    // cell phase: wave 0 -> (h0,c0), wave 4 -> (h1,c1)
    if (tid < HID) {
      if (s < S_LEN) {
        int u = tid;
        float i_ = a0_lds[u], f_ = a0_lds[HID + u], g_ = a0_lds[2 * HID + u], o_ = a0_lds[3 * HID + u];
        cc = f_ * cc + i_ * g_;
        float e2 = __expf(-2.0f * cc);
        float th = 2.0f / (1.0f + e2) - 1.0f;
        float h = o_ * th;
        ((_Float16*)h0h[wb])[u] = (_Float16)h;
        H0S[(size_t)(s + 1) * HID + u] = h;
        C0S[(size_t)(s + 1) * HID + u] = cc;
      }
    } else if (tid >= G4 && tid < G4 + HID) {
      if (s >= 1) {
        int u = tid - G4;
        int t = s - 1;
        float i_ = a1_lds[u], f_ = a1_lds[HID + u], g_ = a1_lds[2 * HID + u], o_ = a1_lds[3 * HID + u];
        cc = f_ * cc + i_ * g_;
        float e2 = __expf(-2.0f * cc);
        float th = 2.0f / (1.0f + e2) - 1.0f;
        float h = o_ * th;
        ((_Float16*)h1h[wb])[u] = (_Float16)h;
        H1S[(size_t)(t + 2) * HID + u] = h;
        C1S[(size_t)(t + 2) * HID + u] = cc;
      }
    }
    asm volatile("s_waitcnt lgkmcnt(0)" ::: "memory");
    __builtin_amdgcn_sched_barrier(0);
    __builtin_amdgcn_s_barrier();
    __builtin_amdgcn_sched_barrier(0);
  }
}

// ---------------- per-t gradient (fully parallel; uses stored activations only) ----------------
__global__ __launch_bounds__(256) void wl_grad_kernel(const float* __restrict__ Wih0,
                                                      const float* __restrict__ Whh0,
                                                      const float* __restrict__ Wih1,
                                                      const float* __restrict__ Whh1,
                                                      float* __restrict__ ws) {
  int t = blockIdx.x;
  int tid = threadIdx.x;
  float* GOH = ws + OFF_GOH;
  float* GWS = ws + OFF_GWS;
  if (t == 0) {  // gohs[0]=0, gws[0]=0
    if (tid < HID) GOH[tid] = 0.0f;
    if (tid < DIN) GWS[tid] = 0.0f;
    return;
  }
  const float* ACT0 = ws + OFF_ACT0;
  const float* ACT1 = ws + OFF_ACT1;
  const float* C0S = ws + OFF_C0S;
  const float* C1S = ws + OFF_C1S;
  __shared__ float a3[G4], am[G4], a0[G4];
  __shared__ float dg3[G4], dg0[G4], dgm[G4];
  __shared__ float dh0n[HID], dh1m[HID], dc1m[HID];
  __shared__ float cbuf[5 * HID];  // c3 | c1m | c1pp | c0n | c0p
  __shared__ float wsum_s[HID];
  a3[tid] = ACT1[(size_t)t * G4 + tid];
  am[tid] = ACT1[(size_t)(t - 1) * G4 + tid];
  a0[tid] = ACT0[(size_t)t * G4 + tid];
  if (tid < HID) {
    cbuf[tid]           = C1S[(size_t)(t + 2) * HID + tid];  // c3  = c1[t]
    cbuf[HID + tid]     = C1S[(size_t)(t + 1) * HID + tid];  // c1m = c1[t-1]
    cbuf[2 * HID + tid] = C1S[(size_t)t * HID + tid];        // c1pp= c1[t-2]
    cbuf[3 * HID + tid] = C0S[(size_t)(t + 1) * HID + tid];  // c0n = c0[t]
    cbuf[4 * HID + tid] = C0S[(size_t)t * HID + tid];        // c0p = c0[t-1]
    wsum_s[tid] = ws[OFF_WSUM + tid];
  }
  __syncthreads();
  // backward through cell3 (== real layer-1 cell at step t)
  if (tid < HID) {
    int k = tid;
    float tc = tanh_(cbuf[k]);
    float si = a3[k], sf = a3[HID + k], tg = a3[2 * HID + k], so = a3[3 * HID + k];
    float dh = wsum_s[k];
    float dov = dh * tc * so * (1.0f - so);
    float dc = dh * so * (1.0f - tc * tc);
    dg3[k] = dc * tg * si * (1.0f - si);
    dg3[HID + k] = dc * cbuf[HID + k] * sf * (1.0f - sf);
    dg3[2 * HID + k] = dc * si * (1.0f - tg * tg);
    dg3[3 * HID + k] = dov;
    dc1m[k] = dc * sf;
  }
  __syncthreads();
  // dh0n = dg3 @ Wih1 ; dh1m = dg3 @ Whh1
  if (tid < HID) {
    float s = 0.0f;
#pragma unroll 8
    for (int j = 0; j < G4; ++j) s += dg3[j] * Wih1[(size_t)j * HID + tid];
    dh0n[tid] = s;
  } else if (tid < 2 * HID) {
    int k = tid - HID;
    float s = 0.0f;
#pragma unroll 8
    for (int j = 0; j < G4; ++j) s += dg3[j] * Whh1[(size_t)j * HID + k];
    dh1m[k] = s;
  }
  __syncthreads();
  // backward through cell0 (dc0n = 0) and cellm (== layer-1 cell at step t-1)
  if (tid < HID) {
    int k = tid;
    float tc = tanh_(cbuf[3 * HID + k]);
    float si = a0[k], sf = a0[HID + k], tg = a0[2 * HID + k], so = a0[3 * HID + k];
    float dh = dh0n[k];
    float dov = dh * tc * so * (1.0f - so);
    float dc = dh * so * (1.0f - tc * tc);
    dg0[k] = dc * tg * si * (1.0f - si);
    dg0[HID + k] = dc * cbuf[4 * HID + k] * sf * (1.0f - sf);
    dg0[2 * HID + k] = dc * si * (1.0f - tg * tg);
    dg0[3 * HID + k] = dov;
  } else if (tid < 2 * HID) {
    int k = tid - HID;
    float tc = tanh_(cbuf[HID + k]);
    float si = am[k], sf = am[HID + k], tg = am[2 * HID + k], so = am[3 * HID + k];
    float dh = dh1m[k];
    float dov = dh * tc * so * (1.0f - so);
    float dc = dh * so * (1.0f - tc * tc) + dc1m[k];
    dgm[k] = dc * tg * si * (1.0f - si);
    dgm[HID + k] = dc * cbuf[2 * HID + k] * sf * (1.0f - sf);
    dgm[2 * HID + k] = dc * si * (1.0f - tg * tg);
    dgm[3 * HID + k] = dov;
  }
  __syncthreads();
  // gws = dg0 @ Wih0 ; gohs = dg0 @ Whh0 + dgm @ Wih1
  if (tid < DIN) {
    float s = 0.0f;
#pragma unroll 8
    for (int j = 0; j < G4; ++j) s += dg0[j] * Wih0[(size_t)j * DIN + tid];
    GWS[(size_t)t * DIN + tid] = s;
  } else if (tid < DIN + HID) {
    int k = tid - DIN;
    float sA = 0.0f, sB = 0.0f;
#pragma unroll 8
    for (int j = 0; j < G4; ++j) {
      sA += dg0[j] * Whh0[(size_t)j * HID + k];
      sB += dgm[j] * Wih1[(size_t)j * HID + k];
    }
    GOH[(size_t)t * HID + k] = sA + sB;
  }
}

// ---------------- outs[t] = Wlin @ h1[t] + blin ----------------
__global__ __launch_bounds__(256) void wl_outs_kernel(const float* __restrict__ Wlin,
                                                      const float* __restrict__ blin,
                                                      const float* __restrict__ ws,
                                                      float* __restrict__ out) {
  int tloc = threadIdx.x >> 5, o = threadIdx.x & 31;
  int t = blockIdx.x * 8 + tloc;
  if (o < NOUT) {
    const float* h1 = ws + OFF_H1S + (size_t)(t + 2) * HID;
    const float* wr = Wlin + o * HID;
    float s = blin[o];
#pragma unroll 8
    for (int k = 0; k < HID; ++k) s += wr[k] * h1[k];
    out[(size_t)t * NOUT + o] = s;
  }
}

// ---------------- column-wise min/max partials for gohs (m=0) and old_hts (m=1) ----------------
__global__ __launch_bounds__(256) void wl_mm_partial_kernel(float* __restrict__ ws) {
  int m = blockIdx.y;
  int col = threadIdx.x & 63, rg = threadIdx.x >> 6;
  const float* src = ws + (m == 0 ? OFF_GOH : OFF_H0S);  // H0S rows 0..8191 == old_hts
  float mn = 3.4e38f, mx = -3.4e38f;
  int r0 = blockIdx.x * 128;
  for (int r = r0 + rg; r < r0 + 128; r += 4) {
    float v = src[(size_t)r * HID + col];
    mn = fminf(mn, v);
    mx = fmaxf(mx, v);
  }
  __shared__ float smn[256], smx[256];
  smn[threadIdx.x] = mn;
  smx[threadIdx.x] = mx;
  __syncthreads();
  if (threadIdx.x < 64) {
    float a = fminf(fminf(smn[col], smn[64 + col]), fminf(smn[128 + col], smn[192 + col]));
    float b = fmaxf(fmaxf(smx[col], smx[64 + col]), fmaxf(smx[128 + col], smx[192 + col]));
    ws[OFF_PMN + ((size_t)m * 64 + blockIdx.x) * 64 + col] = a;
    ws[OFF_PMX + ((size_t)m * 64 + blockIdx.x) * 64 + col] = b;
  }
}

__global__ __launch_bounds__(128) void wl_mm_final_kernel(float* __restrict__ ws) {
  int i = threadIdx.x;
  if (i < 128) {
    int m = i >> 6, col = i & 63;
    float mn = 3.4e38f, mx = -3.4e38f;
    for (int b = 0; b < 64; ++b) {
      mn = fminf(mn, ws[OFF_PMN + ((size_t)m * 64 + b) * 64 + col]);
      mx = fmaxf(mx, ws[OFF_PMX + ((size_t)m * 64 + b) * 64 + col]);
    }
    ws[OFF_MN + i] = mn;
    ws[OFF_INV + i] = 1.0f / (mx - mn + 1e-6f);
  }
}

// ---------------- final: output_data assembly + HPM fwd + F + AllF_x ----------------
__global__ __launch_bounds__(256) void wl_final_kernel(const float* __restrict__ input,
                                                       const float* __restrict__ Whpm1,
                                                       const float* __restrict__ bhpm1,
                                                       const float* __restrict__ Whpm2,
                                                       const float* __restrict__ bhpm2,
                                                       const float* __restrict__ ws,
                                                       float* __restrict__ out) {
  int t = blockIdx.x;
  int tid = threadIdx.x;
  __shared__ float od[DHPM];
  __shared__ float red[256];
  __shared__ float zb[4];
  const float* GOH = ws + OFF_GOH;
  const float* H0S = ws + OFF_H0S;
  const float* MNp = ws + OFF_MN;
  const float* INVp = ws + OFF_INV;
  if (tid < NOUT) {
    od[tid] = out[(size_t)t * NOUT + tid];
  } else if (tid < 74) {
    int k = tid - 10;
    od[tid] = (GOH[(size_t)t * HID + k] - MNp[k]) * INVp[k];
  } else if (tid < 194) {
    int q = tid - 74;
    od[tid] = input[(size_t)t * DIN + q];
  } else {
    int k = tid - 194;
    od[tid] = (H0S[(size_t)t * HID + k] - MNp[64 + k]) * INVp[64 + k];
  }
  if (tid < 2) {
    int k = 62 + tid;
    od[256 + tid] = (H0S[(size_t)t * HID + k] - MNp[64 + k]) * INVp[64 + k];
  }
  __syncthreads();
  // z1pre[0]
  float p = od[tid] * Whpm1[tid];
  if (tid < 2) p += od[256 + tid] * Whpm1[256 + tid];
  red[tid] = p;
  __syncthreads();
  for (int off = 128; off > 0; off >>= 1) {
    if (tid < off) red[tid] += red[tid + off];
    __syncthreads();
  }
  if (tid == 0) zb[0] = red[0];
  __syncthreads();
  // z1pre[1]
  p = od[tid] * Whpm1[DHPM + tid];
  if (tid < 2) p += od[256 + tid] * Whpm1[DHPM + 256 + tid];
  red[tid] = p;
  __syncthreads();
  for (int off = 128; off > 0; off >>= 1) {
    if (tid < off) red[tid] += red[tid + off];
    __syncthreads();
  }
  if (tid == 0) {
    float z0 = tanh_(zb[0] + bhpm1[0]);
    float z1 = tanh_(red[0] + bhpm1[1]);
    zb[0] = z0;
    zb[1] = z1;
    zb[2] = ws[OFF_S2 + 0] * (1.0f - z0 * z0);
    zb[3] = ws[OFF_S2 + 1] * (1.0f - z1 * z1);
  }
  __syncthreads();
  float z0 = zb[0], z1 = zb[1], d0 = zb[2], d1 = zb[3];
  if (tid < DIN) {
    float G = bhpm2[tid] + z0 * Whpm2[tid * 2] + z1 * Whpm2[tid * 2 + 1];
    out[(size_t)S_LEN * NOUT + (size_t)t * DIN + tid] = ws[OFF_GWS + (size_t)t * DIN + tid] - G;
  }
  out[(size_t)S_LEN * (NOUT + DIN) + (size_t)t * DHPM + tid] = -(d0 * Whpm1[tid] + d1 * Whpm1[DHPM + tid]);
  if (tid < 2) {
    int i2 = 256 + tid;
    out[(size_t)S_LEN * (NOUT + DIN) + (size_t)t * DHPM + i2] = -(d0 * Whpm1[i2] + d1 * Whpm1[DHPM + i2]);
  }
}

extern "C" void kernel_launch(void* const* d_in, const int* in_sizes, int n_in,
                              void* d_out, int out_size, void* d_ws, size_t ws_size,
                              hipStream_t stream) {
  const float* input = (const float*)d_in[0];
  const float* Wih0 = (const float*)d_in[1];
  const float* Whh0 = (const float*)d_in[2];
  const float* bih0 = (const float*)d_in[3];
  const float* bhh0 = (const float*)d_in[4];
  const float* Wih1 = (const float*)d_in[5];
  const float* Whh1 = (const float*)d_in[6];
  const float* bih1 = (const float*)d_in[7];
  const float* bhh1 = (const float*)d_in[8];
  const float* Wlin = (const float*)d_in[9];
  const float* blin = (const float*)d_in[10];
  const float* Whpm1 = (const float*)d_in[11];
  const float* bhpm1 = (const float*)d_in[12];
  const float* Whpm2 = (const float*)d_in[13];
  const float* bhpm2 = (const float*)d_in[14];
  float* ws = (float*)d_ws;
  float* out = (float*)d_out;

  wl_prep_kernel<<<1, 128, 0, stream>>>(Wlin, Whpm2, ws);
  wl_pre0_kernel<<<S_LEN / 8, 256, 0, stream>>>(input, Wih0, bih0, bhh0, ws);
  wl_scan_kernel<<<1, 512, 0, stream>>>(Whh0, Wih1, Whh1, bih1, bhh1, ws);
  wl_grad_kernel<<<S_LEN, 256, 0, stream>>>(Wih0, Whh0, Wih1, Whh1, ws);
  wl_outs_kernel<<<S_LEN / 8, 256, 0, stream>>>(Wlin, blin, ws, out);
  wl_mm_partial_kernel<<<dim3(64, 2), 256, 0, stream>>>(ws);
  wl_mm_final_kernel<<<1, 128, 0, stream>>>(ws);
  wl_final_kernel<<<S_LEN, 256, 0, stream>>>(input, Whpm1, bhpm1, Whpm2, bhpm2, ws, out);
}